// Round 8
// baseline (601.009 us; speedup 1.0000x reference)
//
#include <hip/hip_runtime.h>
#include <cstdint>
#include <cstddef>

#define INPUT_DIM 256
#define OUT_DIM   16
#define NMID      784     // middle nodes
#define NNODE     1040
#define MROW      768     // effM row length (middle cols; cols >=768 are in-block only)
#define KB        16      // node block size
#define NBLK      49      // 784 / 16
#define NMCH      24      // middle-state chunks of 32 k-elems (768/32)
#define BATCH     32768
#define UNITW     520     // ushorts per 2-row LDS unit (1040 B; bank-balanced, verified)
#define XROW      264     // pgemm LDS x row stride (528 B)

typedef float f32x4 __attribute__((ext_vector_type(4)));
typedef __bf16 bf16x8 __attribute__((ext_vector_type(8)));

#define GLL16(gp, lp)                                                        \
  __builtin_amdgcn_global_load_lds(                                          \
      (const __attribute__((address_space(1))) unsigned int*)(gp),           \
      (__attribute__((address_space(3))) unsigned int*)(lp), 16, 0, 0)

static __device__ __forceinline__ unsigned int f2bf(float f) {
  unsigned int u = __builtin_bit_cast(unsigned int, f);
  u += 0x7fffu + ((u >> 16) & 1u);   // round-to-nearest-even
  return u >> 16;
}
static __device__ __forceinline__ float bf2f(unsigned short h) {
  unsigned int u = ((unsigned int)h) << 16;
  return __builtin_bit_cast(float, u);
}
static __device__ __forceinline__ float bflo(unsigned int w) {
  return __builtin_bit_cast(float, w << 16);
}
static __device__ __forceinline__ float bfhi(unsigned int w) {
  return __builtin_bit_cast(float, w & 0xffff0000u);
}

// ---------------------------------------------------------------------------
// Prep 1: split masked weights into
//   effX[i][k]  = w[k][i]*conn[k][i]              (k<256, always causal), bf16
//   effM[i][jm] = w[256+jm][i]*conn*ex[jm]*(jm<i) (jm<768; >=768 is in-block)
// ---------------------------------------------------------------------------
__global__ __launch_bounds__(256) void prep_efft(
    const float* __restrict__ w, const int* __restrict__ conn,
    const int* __restrict__ ex, unsigned short* __restrict__ effX,
    unsigned short* __restrict__ effM) {
  __shared__ unsigned short tile[64][66];
  const int j0 = blockIdx.x * 64;
  const int i0 = blockIdx.y * 64;
  const int tx = threadIdx.x & 63;   // i offset
  const int ty = threadIdx.x >> 6;   // j sub-row
  const int i  = i0 + tx;
  for (int t = 0; t < 16; ++t) {
    int j = j0 + t * 4 + ty;
    float v = 0.f;
    if (j < NNODE && i < NMID && j < INPUT_DIM + i) {
      float e = (j >= INPUT_DIM) ? (float)ex[j - INPUT_DIM] : 1.f;
      v = w[(size_t)j * NMID + i] * (float)conn[(size_t)j * NMID + i] * e;
    }
    tile[t * 4 + ty][tx] = (unsigned short)f2bf(v);
  }
  __syncthreads();
  const int i_loc = threadIdx.x >> 2;
  const int jq    = threadIdx.x & 3;
  const int iw    = i0 + i_loc;
  const int jbase = j0 + jq * 16;
  if (iw < NMID) {
    if (jbase + 16 <= INPUT_DIM) {
      #pragma unroll
      for (int c = 0; c < 16; ++c)
        effX[(size_t)iw * INPUT_DIM + jbase + c] = tile[jq * 16 + c][i_loc];
    } else if (jbase >= INPUT_DIM && (jbase - INPUT_DIM + 16) <= MROW) {
      #pragma unroll
      for (int c = 0; c < 16; ++c)
        effM[(size_t)iw * MROW + (jbase - INPUT_DIM) + c] =
            tile[jq * 16 + c][i_loc];
    }
  }
}

// ---------------------------------------------------------------------------
// Prep 2: cvec[i] = sum_jm effweight[jm->i] * bias[jm]  (bias folded constant)
// ---------------------------------------------------------------------------
__global__ __launch_bounds__(64) void prep_cvec(
    const unsigned short* __restrict__ effM, const float* __restrict__ w,
    const int* __restrict__ conn, const int* __restrict__ ex,
    const float* __restrict__ bias, float* __restrict__ cvec) {
  const int i = blockIdx.x;
  const int l = threadIdx.x;
  float s = 0.f;
  for (int jm = l; jm < MROW; jm += 64)
    s += bf2f(effM[(size_t)i * MROW + jm]) * bias[jm];
  {
    int jm = MROW + l;                 // valid only 768..783
    if (jm < NMID && jm < i) {
      size_t idx = (size_t)(INPUT_DIM + jm) * NMID + i;
      s += w[idx] * (float)conn[idx] * (float)ex[jm] * bias[jm];
    }
  }
  for (int off = 32; off; off >>= 1) s += __shfl_down(s, off, 64);
  if (l == 0) cvec[i] = s;
}

// ---------------------------------------------------------------------------
// Prep 3: wpk[b][k][c] (f32): k<c -> w[256+16b+k][16b+c]*conn*ex[16b+k]
//                             k==c -> cvec[16b+k]; k>c -> 0
// ---------------------------------------------------------------------------
__global__ __launch_bounds__(256) void prep_wpack(
    const float* __restrict__ w, const int* __restrict__ conn,
    const int* __restrict__ ex, const float* __restrict__ cvec,
    float* __restrict__ wpk) {
  const int b = blockIdx.x;
  const int k = threadIdx.x >> 4;
  const int c = threadIdx.x & 15;
  const int src = KB * b + k;
  const int dst = KB * b + c;
  float v = 0.f;
  if (k < c) {
    size_t idx = (size_t)(INPUT_DIM + src) * NMID + dst;
    v = w[idx] * (float)conn[idx] * (float)ex[src];
  } else if (k == c) {
    v = cvec[src];
  }
  wpk[b * 256 + k * 16 + c] = v;
}

// ---------------------------------------------------------------------------
// P-GEMM: Pt2[bblk][nb][r16][c] = sum_k effX[nb*16+c][k]*x[bblk*16+r16][k]
// (bf16). Block = 256 thr; stage x[64][256] bf16 to LDS once; waves then
// loop node-blocks independently. C layout -> one contiguous uint2 store.
// ---------------------------------------------------------------------------
__global__ __launch_bounds__(256)
__attribute__((amdgpu_waves_per_eu(2, 4))) void pgemm(
    const float* __restrict__ x, const unsigned short* __restrict__ effX,
    unsigned short* __restrict__ Pt, int slab_off, int slabsz) {
  __shared__ __align__(16) unsigned short xs[64][XROW];   // 33792 B

  const int tid = threadIdx.x;
  const int l   = tid & 63;
  const int wv  = tid >> 6;
  const int g   = l >> 4;
  const int r16 = l & 15;
  const int bb  = blockIdx.x * 64;          // slab-local batch base

  // ---- stage x tile as bf16 ----
  {
    const int row = tid >> 2;
    const int q   = tid & 3;
    const float* xr = x + (size_t)(slab_off + bb + row) * INPUT_DIM + q * 64;
    unsigned short* xd = &xs[row][q * 64];
    #pragma unroll
    for (int i = 0; i < 16; ++i) {
      float4 v = *(const float4*)(xr + 4 * i);
      uint2 u;
      u.x = f2bf(v.x) | (f2bf(v.y) << 16);
      u.y = f2bf(v.z) | (f2bf(v.w) << 16);
      *(uint2*)(xd + 4 * i) = u;
    }
  }
  __syncthreads();

  for (int nb = wv; nb < NBLK; nb += 4) {
    const unsigned short* ap =
        effX + (size_t)(nb * 16 + r16) * INPUT_DIM + 8 * g;
    uint4 a[8];
    #pragma unroll
    for (int c = 0; c < 8; ++c) a[c] = *(const uint4*)(ap + 32 * c);

    #pragma unroll
    for (int s = 0; s < 4; ++s) {
      f32x4 acc = {0.f, 0.f, 0.f, 0.f};
      #pragma unroll
      for (int c = 0; c < 8; ++c) {
        uint4 braw = *(const uint4*)&xs[s * 16 + r16][32 * c + 8 * g];
        acc = __builtin_amdgcn_mfma_f32_16x16x32_bf16(
            __builtin_bit_cast(bf16x8, a[c]), __builtin_bit_cast(bf16x8, braw),
            acc, 0, 0, 0);
      }
      // lane holds nodes {4g..4g+3} of nb for batch row bb+16s+r16
      uint2 u;
      u.x = f2bf(acc[0]) | (f2bf(acc[1]) << 16);
      u.y = f2bf(acc[2]) | (f2bf(acc[3]) << 16);
      *(uint2*)&Pt[((size_t)(((bb >> 4) + s) * NBLK + nb) << 8) +
                   r16 * 16 + 4 * g] = u;
    }
  }
}

// ---------------------------------------------------------------------------
// Main sequential kernel, operand-swapped GEMM:
//   D = mfma(A=W_tile(LDS), B=sfrag) -> lane (g,r16) holds 4 node-logits for
//   its OWN batch row r16 -> no LDS transpose. Butterfly all-gather
//   (12 ds_bpermute) gives every lane all 16 logits; redundant in-reg solve
//   with f32 wtri; pack into owning fragment reg. One barrier per block.
// LDS 51968 B -> 3 wg/CU; waves_per_eu(3,4) caps regs ~168 (demand ~155).
// ---------------------------------------------------------------------------
__global__ __launch_bounds__(256)
__attribute__((amdgpu_waves_per_eu(3, 4))) void net_main(
    const unsigned short* __restrict__ Pt,
    const unsigned short* __restrict__ effM,
    const float* __restrict__ wpk,
    const float* __restrict__ bias, const int* __restrict__ ex,
    float* __restrict__ out, int slab_off, int slabsz) {
  __shared__ __align__(16) unsigned short Bs[2][3][8][UNITW];  // 49920 B
  __shared__ __align__(16) float wtriF[2][256];                //  2048 B

  const int tid = threadIdx.x;
  const int l   = tid & 63;
  const int wv  = tid >> 6;
  const int g   = l >> 4;
  const int r16 = l & 15;
  const int rb  = (blockIdx.x * 4 + wv) * 16;   // slab-local batch base
  const int idx16 = (l ^ 16) << 2;              // bpermute byte indices
  const int idx32 = (l ^ 32) << 2;

  uint4 sfrag[NMCH];
  #pragma unroll
  for (int c = 0; c < NMCH; ++c) {
    uint4 z; z.x = z.y = z.z = z.w = 0u;
    sfrag[c] = z;
  }

  // Stage B rows of block t into buffer nb (layout & swizzle unchanged;
  // bank balance verified by enumeration).
#define STAGE_B(nb, t)                                                        \
  {                                                                           \
    _Pragma("unroll")                                                         \
    for (int q_ = 0; q_ < 2; ++q_) {                                          \
      const int rp_ = wv + 4 * q_;           /* unit 0..7 */                  \
      const int r_  = 2 * rp_ + (l >> 5);    /* B-row 0..15 */                \
      const int cl_ = (l & 31) ^ (r_ & 7);                                    \
      const unsigned short* gs_ =                                             \
          effM + (size_t)(16 * (t) + r_) * MROW + cl_ * 8;                    \
      GLL16(gs_, &Bs[nb][0][rp_][0]);                                         \
      if ((t) >= 17) GLL16(gs_ + 256, &Bs[nb][1][rp_][0]);                    \
      if ((t) >= 33) GLL16(gs_ + 512, &Bs[nb][2][rp_][0]);                    \
    }                                                                         \
  }

  // prologue: wtri for block 0
  if (wv == 0)
    *(float4*)&wtriF[0][l * 4] = *(const float4*)(wpk + l * 4);
  __syncthreads();

  for (int b = 0; b < NBLK; ++b) {
    const int cur = b & 1;

    if (b + 1 < NBLK) {
      STAGE_B(cur ^ 1, b + 1);
      if (wv == 0)
        *(float4*)&wtriF[cur ^ 1][l * 4] =
            *(const float4*)(wpk + (b + 1) * 256 + l * 4);
    }

    // Pt (x contribution): issue early, consume after GEMM.
    uint2 praw = *(const uint2*)&Pt[((size_t)((rb >> 4) * NBLK + b) << 8) +
                                    r16 * 16 + 4 * g];

    // ---- GEMM, swapped operands: D[node][batch] ----
    f32x4 ac0 = {0.f, 0.f, 0.f, 0.f}, ac1 = ac0, ac2 = ac0, ac3 = ac0;
#define CHUNK(c)                                                              \
  {                                                                           \
    const int pp_ = (c) >> 3, cc_ = (c) & 7;                                  \
    uint4 braw = *(const uint4*)&Bs[cur][pp_][r16 >> 1]                       \
        [(r16 & 1) * 256 + (((cc_ * 4 + g) ^ (r16 & 7)) * 8)];                \
    f32x4& a_ = ((c) & 3) == 0 ? ac0 : ((c) & 3) == 1 ? ac1                   \
               : ((c) & 3) == 2 ? ac2 : ac3;                                  \
    a_ = __builtin_amdgcn_mfma_f32_16x16x32_bf16(                             \
        __builtin_bit_cast(bf16x8, braw),                                     \
        __builtin_bit_cast(bf16x8, sfrag[(c)]), a_, 0, 0, 0);                 \
  }
    if (b >= 1) {
      CHUNK(0) CHUNK(1) CHUNK(2) CHUNK(3)
      CHUNK(4) CHUNK(5) CHUNK(6) CHUNK(7)
    }
    if (b >= 17) {
      CHUNK(8) CHUNK(9) CHUNK(10) CHUNK(11)
      CHUNK(12) CHUNK(13) CHUNK(14) CHUNK(15)
    }
    if (b >= 33) {
      CHUNK(16) CHUNK(17) CHUNK(18) CHUNK(19)
      CHUNK(20) CHUNK(21) CHUNK(22) CHUNK(23)
    }
#undef CHUNK
    f32x4 accsum = (ac0 + ac1) + (ac2 + ac3);
    // lane (g,r16): logits for nodes 16b+4g+i, batch row rb+r16
    float v0 = accsum[0] + bflo(praw.x);
    float v1 = accsum[1] + bfhi(praw.x);
    float v2 = accsum[2] + bflo(praw.y);
    float v3 = accsum[3] + bfhi(praw.y);

    // ---- butterfly all-gather: all 16 logits into every lane ----
    float q0 = __builtin_bit_cast(float,
        __builtin_amdgcn_ds_bpermute(idx16, __builtin_bit_cast(int, v0)));
    float q1 = __builtin_bit_cast(float,
        __builtin_amdgcn_ds_bpermute(idx16, __builtin_bit_cast(int, v1)));
    float q2 = __builtin_bit_cast(float,
        __builtin_amdgcn_ds_bpermute(idx16, __builtin_bit_cast(int, v2)));
    float q3 = __builtin_bit_cast(float,
        __builtin_amdgcn_ds_bpermute(idx16, __builtin_bit_cast(int, v3)));
    const bool glo = (g & 1) == 0;
    float p8[8];
    p8[0] = glo ? v0 : q0;
    p8[1] = glo ? v1 : q1;
    p8[2] = glo ? v2 : q2;
    p8[3] = glo ? v3 : q3;
    p8[4] = glo ? q0 : v0;
    p8[5] = glo ? q1 : v1;
    p8[6] = glo ? q2 : v2;
    p8[7] = glo ? q3 : v3;
    const bool plo = g < 2;
    float acc_t[16];
    #pragma unroll
    for (int j = 0; j < 8; ++j) {
      float rj = __builtin_bit_cast(float,
          __builtin_amdgcn_ds_bpermute(idx32, __builtin_bit_cast(int, p8[j])));
      acc_t[j]     = plo ? p8[j] : rj;
      acc_t[8 + j] = plo ? rj : p8[j];
    }

    // ---- triangular solve: f32 wtri, uniform broadcast reads ----
    const float* wt = &wtriF[cur][0];
    #pragma unroll
    for (int k = 0; k < 16; ++k) {
      float wr[16];
      #pragma unroll
      for (int q = k >> 2; q < 4; ++q) {
        float4 wq = *(const float4*)(wt + k * 16 + q * 4);
        wr[q * 4 + 0] = wq.x; wr[q * 4 + 1] = wq.y;
        wr[q * 4 + 2] = wq.z; wr[q * 4 + 3] = wq.w;
      }
      float xk = acc_t[k] + wr[k];              // diag carries cvec
      float s  = __builtin_amdgcn_rcpf(
          1.f + __builtin_amdgcn_exp2f(xk * -1.44269504088896341f));
      acc_t[k] = s;
      #pragma unroll
      for (int c = k + 1; c < 16; ++c)
        acc_t[c] = __builtin_fmaf(s, wr[c], acc_t[c]);
    }

    if (b == NBLK - 1) {
      const size_t orow = (size_t)(slab_off + rb + r16) * OUT_DIM;
      #pragma unroll
      for (int i = 0; i < 4; ++i) {
        float a01 = (g & 1) ? acc_t[4 + i] : acc_t[i];
        float a23 = (g & 1) ? acc_t[12 + i] : acc_t[8 + i];
        float ov  = (g & 2) ? a23 : a01;
        int oc = 4 * g + i;
        int mi = NMID - OUT_DIM + oc;
        out[orow + oc] = (ov + bias[mi]) * (float)ex[mi];
      }
    } else {
      // pack 16 new values into the owning middle-chunk register
      float pv[8];
      #pragma unroll
      for (int j = 0; j < 8; ++j)
        pv[j] = (g & 1) ? acc_t[8 + j] : acc_t[j];
      uint4 packed;
      packed.x = f2bf(pv[0]) | (f2bf(pv[1]) << 16);
      packed.y = f2bf(pv[2]) | (f2bf(pv[3]) << 16);
      packed.z = f2bf(pv[4]) | (f2bf(pv[5]) << 16);
      packed.w = f2bf(pv[6]) | (f2bf(pv[7]) << 16);
      const bool part = ((g >> 1) == (b & 1));
      const int cml = (b >> 1) & 7;
#define PACKW(base)                                                           \
  {                                                                           \
    _Pragma("unroll")                                                         \
    for (int c2 = 0; c2 < 8; ++c2)                                            \
      if (c2 == cml) {                                                        \
        if (part) sfrag[(base) + c2] = packed;                                \
      }                                                                       \
  }
      if (b < 16) {
        PACKW(0)
      } else if (b < 32) {
        PACKW(8)
      } else {
        PACKW(16)
      }
#undef PACKW
    }

    __syncthreads();   // publish staged B/wtri; prior LDS reads done
  }
#undef STAGE_B
}

// ---------------------------------------------------------------------------
extern "C" void kernel_launch(void* const* d_in, const int* in_sizes, int n_in,
                              void* d_out, int out_size, void* d_ws, size_t ws_size,
                              hipStream_t stream) {
  const float* x      = (const float*)d_in[0];
  const float* weight = (const float*)d_in[1];
  const float* bias   = (const float*)d_in[2];
  const int*   conn   = (const int*)d_in[3];
  const int*   ex     = (const int*)d_in[4];

  char* ws = (char*)d_ws;
  size_t off = 0;
  unsigned short* effX = (unsigned short*)(ws + off); off += (size_t)NMID * INPUT_DIM * 2;
  unsigned short* effM = (unsigned short*)(ws + off); off += (size_t)NMID * MROW * 2;
  float*          cvec = (float*)(ws + off);          off += (size_t)NMID * 4;
  float*          wpk  = (float*)(ws + off);          off += (size_t)NBLK * 256 * 4;
  off = (off + 255) & ~(size_t)255;
  const size_t fixed = off;

  // Pt slab sizing (bytes per slab = slabsz*NBLK*16*... = slabsz*784*2)
  int nslabs = 1;
  while (nslabs < 16 &&
         fixed + (size_t)(BATCH / nslabs) * NBLK * 16 * 2 > ws_size)
    nslabs <<= 1;
  const int slabsz = BATCH / nslabs;
  unsigned short* Pt = (unsigned short*)(ws + fixed);

  prep_efft<<<dim3(16, 13), 256, 0, stream>>>(weight, conn, ex, effX, effM);
  prep_cvec<<<dim3(NMID), 64, 0, stream>>>(effM, weight, conn, ex, bias, cvec);
  prep_wpack<<<dim3(NBLK), 256, 0, stream>>>(weight, conn, ex, cvec, wpk);

  for (int s = 0; s < nslabs; ++s) {
    pgemm<<<dim3(slabsz / 64), 256, 0, stream>>>(
        x, effX, Pt, s * slabsz, slabsz);
    net_main<<<dim3(slabsz / 64), 256, 0, stream>>>(
        Pt, effM, wpk, bias, ex, (float*)d_out, s * slabsz, slabsz);
  }
}

// Round 9
// 311.588 us; speedup vs baseline: 1.9289x; 1.9289x over previous
//
#include <hip/hip_runtime.h>
#include <cstdint>
#include <cstddef>

#define INPUT_DIM 256
#define OUT_DIM   16
#define NMID      784     // middle nodes
#define NNODE     1040
#define MROW      768     // effM row length (middle cols; cols >=768 are in-block only)
#define KB        16      // node block size
#define NBLK      49      // 784 / 16
#define NMCH      24      // middle-state chunks of 32 k-elems (768/32)
#define BATCH     32768
#define UNITW     520     // ushorts per 2-row LDS unit (1040 B)
#define XROW      264     // pgemm LDS x row stride (528 B)

typedef float f32x4 __attribute__((ext_vector_type(4)));
typedef __bf16 bf16x8 __attribute__((ext_vector_type(8)));

#define GLL16(gp, lp)                                                        \
  __builtin_amdgcn_global_load_lds(                                          \
      (const __attribute__((address_space(1))) unsigned int*)(gp),           \
      (__attribute__((address_space(3))) unsigned int*)(lp), 16, 0, 0)

#define CVT_PK(dst, lo, hi)                                                  \
  asm("v_cvt_pk_bf16_f32 %0, %1, %2" : "=v"(dst) : "v"(lo), "v"(hi))

static __device__ __forceinline__ unsigned int f2bf(float f) {
  unsigned int u = __builtin_bit_cast(unsigned int, f);
  u += 0x7fffu + ((u >> 16) & 1u);   // round-to-nearest-even
  return u >> 16;
}
static __device__ __forceinline__ float bf2f(unsigned short h) {
  unsigned int u = ((unsigned int)h) << 16;
  return __builtin_bit_cast(float, u);
}
static __device__ __forceinline__ float bflo(unsigned int w) {
  return __builtin_bit_cast(float, w << 16);
}
static __device__ __forceinline__ float bfhi(unsigned int w) {
  return __builtin_bit_cast(float, w & 0xffff0000u);
}

// ---------------------------------------------------------------------------
// Prep 1: split masked weights into
//   effX[i][k]  = w[k][i]*conn[k][i]              (k<256, always causal), bf16
//   effM[i][jm] = w[256+jm][i]*conn*ex[jm]*(jm<i) (jm<768; >=768 is in-block)
// ---------------------------------------------------------------------------
__global__ __launch_bounds__(256) void prep_efft(
    const float* __restrict__ w, const int* __restrict__ conn,
    const int* __restrict__ ex, unsigned short* __restrict__ effX,
    unsigned short* __restrict__ effM) {
  __shared__ unsigned short tile[64][66];
  const int j0 = blockIdx.x * 64;
  const int i0 = blockIdx.y * 64;
  const int tx = threadIdx.x & 63;   // i offset
  const int ty = threadIdx.x >> 6;   // j sub-row
  const int i  = i0 + tx;
  for (int t = 0; t < 16; ++t) {
    int j = j0 + t * 4 + ty;
    float v = 0.f;
    if (j < NNODE && i < NMID && j < INPUT_DIM + i) {
      float e = (j >= INPUT_DIM) ? (float)ex[j - INPUT_DIM] : 1.f;
      v = w[(size_t)j * NMID + i] * (float)conn[(size_t)j * NMID + i] * e;
    }
    tile[t * 4 + ty][tx] = (unsigned short)f2bf(v);
  }
  __syncthreads();
  const int i_loc = threadIdx.x >> 2;
  const int jq    = threadIdx.x & 3;
  const int iw    = i0 + i_loc;
  const int jbase = j0 + jq * 16;
  if (iw < NMID) {
    if (jbase + 16 <= INPUT_DIM) {
      #pragma unroll
      for (int c = 0; c < 16; ++c)
        effX[(size_t)iw * INPUT_DIM + jbase + c] = tile[jq * 16 + c][i_loc];
    } else if (jbase >= INPUT_DIM && (jbase - INPUT_DIM + 16) <= MROW) {
      #pragma unroll
      for (int c = 0; c < 16; ++c)
        effM[(size_t)iw * MROW + (jbase - INPUT_DIM) + c] =
            tile[jq * 16 + c][i_loc];
    }
  }
}

// ---------------------------------------------------------------------------
// Prep 2: cvec[i] = sum_jm effweight[jm->i] * bias[jm]  (bias folded constant)
// ---------------------------------------------------------------------------
__global__ __launch_bounds__(64) void prep_cvec(
    const unsigned short* __restrict__ effM, const float* __restrict__ w,
    const int* __restrict__ conn, const int* __restrict__ ex,
    const float* __restrict__ bias, float* __restrict__ cvec) {
  const int i = blockIdx.x;
  const int l = threadIdx.x;
  float s = 0.f;
  for (int jm = l; jm < MROW; jm += 64)
    s += bf2f(effM[(size_t)i * MROW + jm]) * bias[jm];
  {
    int jm = MROW + l;                 // valid only 768..783
    if (jm < NMID && jm < i) {
      size_t idx = (size_t)(INPUT_DIM + jm) * NMID + i;
      s += w[idx] * (float)conn[idx] * (float)ex[jm] * bias[jm];
    }
  }
  for (int off = 32; off; off >>= 1) s += __shfl_down(s, off, 64);
  if (l == 0) cvec[i] = s;
}

// ---------------------------------------------------------------------------
// Prep 3: wpk[b][k][c] (f32): k<c -> w[256+16b+k][16b+c]*conn*ex[16b+k]
//                             k==c -> cvec[16b+k]; k>c -> 0
// ---------------------------------------------------------------------------
__global__ __launch_bounds__(256) void prep_wpack(
    const float* __restrict__ w, const int* __restrict__ conn,
    const int* __restrict__ ex, const float* __restrict__ cvec,
    float* __restrict__ wpk) {
  const int b = blockIdx.x;
  const int k = threadIdx.x >> 4;
  const int c = threadIdx.x & 15;
  const int src = KB * b + k;
  const int dst = KB * b + c;
  float v = 0.f;
  if (k < c) {
    size_t idx = (size_t)(INPUT_DIM + src) * NMID + dst;
    v = w[idx] * (float)conn[idx] * (float)ex[src];
  } else if (k == c) {
    v = cvec[src];
  }
  wpk[b * 256 + k * 16 + c] = v;
}

// ---------------------------------------------------------------------------
// P-GEMM: Pt[bblk][nb][r16][c] = sum_k effX[nb*16+c][k]*x[bblk*16+r16][k]
// (bf16). Block = 256 thr; stage x[64][256] bf16 to LDS once; waves then
// loop node-blocks independently. C layout -> one contiguous uint2 store.
// ---------------------------------------------------------------------------
__global__ __launch_bounds__(256)
__attribute__((amdgpu_waves_per_eu(2, 4))) void pgemm(
    const float* __restrict__ x, const unsigned short* __restrict__ effX,
    unsigned short* __restrict__ Pt, int slab_off, int slabsz) {
  __shared__ __align__(16) unsigned short xs[64][XROW];   // 33792 B

  const int tid = threadIdx.x;
  const int l   = tid & 63;
  const int wv  = tid >> 6;
  const int g   = l >> 4;
  const int r16 = l & 15;
  const int bb  = blockIdx.x * 64;          // slab-local batch base

  // ---- stage x tile as bf16 ----
  {
    const int row = tid >> 2;
    const int q   = tid & 3;
    const float* xr = x + (size_t)(slab_off + bb + row) * INPUT_DIM + q * 64;
    unsigned short* xd = &xs[row][q * 64];
    #pragma unroll
    for (int i = 0; i < 16; ++i) {
      float4 v = *(const float4*)(xr + 4 * i);
      uint2 u;
      u.x = f2bf(v.x) | (f2bf(v.y) << 16);
      u.y = f2bf(v.z) | (f2bf(v.w) << 16);
      *(uint2*)(xd + 4 * i) = u;
    }
  }
  __syncthreads();

  for (int nb = wv; nb < NBLK; nb += 4) {
    const unsigned short* ap =
        effX + (size_t)(nb * 16 + r16) * INPUT_DIM + 8 * g;
    uint4 a[8];
    #pragma unroll
    for (int c = 0; c < 8; ++c) a[c] = *(const uint4*)(ap + 32 * c);

    #pragma unroll
    for (int s = 0; s < 4; ++s) {
      f32x4 acc = {0.f, 0.f, 0.f, 0.f};
      #pragma unroll
      for (int c = 0; c < 8; ++c) {
        uint4 braw = *(const uint4*)&xs[s * 16 + r16][32 * c + 8 * g];
        acc = __builtin_amdgcn_mfma_f32_16x16x32_bf16(
            __builtin_bit_cast(bf16x8, a[c]), __builtin_bit_cast(bf16x8, braw),
            acc, 0, 0, 0);
      }
      uint2 u;
      u.x = f2bf(acc[0]) | (f2bf(acc[1]) << 16);
      u.y = f2bf(acc[2]) | (f2bf(acc[3]) << 16);
      *(uint2*)&Pt[((size_t)(((bb >> 4) + s) * NBLK + nb) << 8) +
                   r16 * 16 + 4 * g] = u;
    }
  }
}

// ---------------------------------------------------------------------------
// Main sequential kernel, operand-swapped GEMM (D[node][batch]):
//   no LDS transpose; butterfly ds_bpermute all-gather; redundant in-reg
//   triangular solve with f32 wtri broadcast reads; pack into owning frag
//   reg via v_cvt_pk_bf16_f32. Pair-unrolled block loop -> compile-time CUR
//   -> all chunk/wtri LDS reads are base-reg + immediate offset (zero VALU).
// waves_per_eu(2,2): proven no-spill point (r7); >2 spills sfrag (r5/r8).
// ---------------------------------------------------------------------------
__global__ __launch_bounds__(256)
__attribute__((amdgpu_waves_per_eu(2, 2))) void net_main(
    const unsigned short* __restrict__ Pt,
    const unsigned short* __restrict__ effM,
    const float* __restrict__ wpk,
    const float* __restrict__ bias, const int* __restrict__ ex,
    float* __restrict__ out, int slab_off, int slabsz) {
  __shared__ __align__(16) unsigned short Bs[2][3][8][UNITW];  // 49920 B
  __shared__ __align__(16) float wtriF[2][256];                //  2048 B

  const int tid = threadIdx.x;
  const int l   = tid & 63;
  const int wv  = tid >> 6;
  const int g   = l >> 4;
  const int r16 = l & 15;
  const int rb  = (blockIdx.x * 4 + wv) * 16;   // slab-local batch base
  const int idx16 = (l ^ 16) << 2;              // bpermute byte indices
  const int idx32 = (l ^ 32) << 2;

  // per-lane byte offsets of the 8 chunk slots (cur=0, pp=0)
  unsigned int boff[8];
  #pragma unroll
  for (int cc = 0; cc < 8; ++cc)
    boff[cc] = (unsigned int)((r16 >> 1) * 1040 + (r16 & 1) * 512 +
                              (((cc * 4 + g) ^ (r16 & 7)) << 4));

  uint4 sfrag[NMCH];
  #pragma unroll
  for (int c = 0; c < NMCH; ++c) {
    uint4 z; z.x = z.y = z.z = z.w = 0u;
    sfrag[c] = z;
  }

#define STAGE_B(nb, t)                                                        \
  {                                                                           \
    _Pragma("unroll")                                                         \
    for (int q_ = 0; q_ < 2; ++q_) {                                          \
      const int rp_ = wv + 4 * q_;           /* unit 0..7 */                  \
      const int r_  = 2 * rp_ + (l >> 5);    /* B-row 0..15 */                \
      const int cl_ = (l & 31) ^ (r_ & 7);                                    \
      const unsigned short* gs_ =                                             \
          effM + (size_t)(16 * (t) + r_) * MROW + cl_ * 8;                    \
      GLL16(gs_, &Bs[nb][0][rp_][0]);                                         \
      if ((t) >= 17) GLL16(gs_ + 256, &Bs[nb][1][rp_][0]);                    \
      if ((t) >= 33) GLL16(gs_ + 512, &Bs[nb][2][rp_][0]);                    \
    }                                                                         \
  }

#define CHUNK(c, CUR)                                                         \
  {                                                                           \
    uint4 braw = *(const uint4*)((const char*)Bs + boff[(c) & 7] +            \
                                 ((CUR) * 24960 + ((c) >> 3) * 8320));        \
    f32x4& a_ = ((c) & 3) == 0 ? ac0 : ((c) & 3) == 1 ? ac1                   \
               : ((c) & 3) == 2 ? ac2 : ac3;                                  \
    a_ = __builtin_amdgcn_mfma_f32_16x16x32_bf16(                             \
        __builtin_bit_cast(bf16x8, braw),                                     \
        __builtin_bit_cast(bf16x8, sfrag[(c)]), a_, 0, 0, 0);                 \
  }

#define BODY(b, CUR)                                                          \
  do {                                                                        \
    if ((b) + 1 < NBLK) {                                                     \
      STAGE_B((CUR) ^ 1, (b) + 1);                                            \
      if (wv == 0)                                                            \
        *(float4*)&wtriF[(CUR) ^ 1][l * 4] =                                  \
            *(const float4*)(wpk + ((b) + 1) * 256 + l * 4);                  \
    }                                                                         \
    uint2 praw = *(const uint2*)&Pt[((size_t)((rb >> 4) * NBLK + (b)) << 8) + \
                                    r16 * 16 + 4 * g];                        \
    f32x4 ac0 = {0.f, 0.f, 0.f, 0.f}, ac1 = ac0, ac2 = ac0, ac3 = ac0;        \
    if ((b) >= 1) {                                                           \
      CHUNK(0, CUR) CHUNK(1, CUR) CHUNK(2, CUR) CHUNK(3, CUR)                 \
      CHUNK(4, CUR) CHUNK(5, CUR) CHUNK(6, CUR) CHUNK(7, CUR)                 \
    }                                                                         \
    if ((b) >= 17) {                                                          \
      CHUNK(8, CUR) CHUNK(9, CUR) CHUNK(10, CUR) CHUNK(11, CUR)               \
      CHUNK(12, CUR) CHUNK(13, CUR) CHUNK(14, CUR) CHUNK(15, CUR)             \
    }                                                                         \
    if ((b) >= 33) {                                                          \
      CHUNK(16, CUR) CHUNK(17, CUR) CHUNK(18, CUR) CHUNK(19, CUR)             \
      CHUNK(20, CUR) CHUNK(21, CUR) CHUNK(22, CUR) CHUNK(23, CUR)             \
    }                                                                         \
    f32x4 accsum = (ac0 + ac1) + (ac2 + ac3);                                 \
    float v0 = accsum[0] + bflo(praw.x);                                      \
    float v1 = accsum[1] + bfhi(praw.x);                                      \
    float v2 = accsum[2] + bflo(praw.y);                                      \
    float v3 = accsum[3] + bfhi(praw.y);                                      \
    float q0 = __builtin_bit_cast(float,                                      \
        __builtin_amdgcn_ds_bpermute(idx16, __builtin_bit_cast(int, v0)));    \
    float q1 = __builtin_bit_cast(float,                                      \
        __builtin_amdgcn_ds_bpermute(idx16, __builtin_bit_cast(int, v1)));    \
    float q2 = __builtin_bit_cast(float,                                      \
        __builtin_amdgcn_ds_bpermute(idx16, __builtin_bit_cast(int, v2)));    \
    float q3 = __builtin_bit_cast(float,                                      \
        __builtin_amdgcn_ds_bpermute(idx16, __builtin_bit_cast(int, v3)));    \
    const bool glo = (g & 1) == 0;                                            \
    float p8[8];                                                              \
    p8[0] = glo ? v0 : q0;  p8[1] = glo ? v1 : q1;                            \
    p8[2] = glo ? v2 : q2;  p8[3] = glo ? v3 : q3;                            \
    p8[4] = glo ? q0 : v0;  p8[5] = glo ? q1 : v1;                            \
    p8[6] = glo ? q2 : v2;  p8[7] = glo ? q3 : v3;                            \
    const bool plo = g < 2;                                                   \
    float acc_t[16];                                                          \
    _Pragma("unroll")                                                         \
    for (int j = 0; j < 8; ++j) {                                             \
      float rj = __builtin_bit_cast(float,                                    \
          __builtin_amdgcn_ds_bpermute(idx32,                                 \
                                       __builtin_bit_cast(int, p8[j])));      \
      acc_t[j]     = plo ? p8[j] : rj;                                        \
      acc_t[8 + j] = plo ? rj : p8[j];                                        \
    }                                                                         \
    _Pragma("unroll")                                                         \
    for (int k = 0; k < 16; ++k) {                                            \
      float wr[16];                                                           \
      _Pragma("unroll")                                                       \
      for (int q = k >> 2; q < 4; ++q) {                                      \
        float4 wq = *(const float4*)(&wtriF[CUR][k * 16 + q * 4]);            \
        wr[q * 4 + 0] = wq.x; wr[q * 4 + 1] = wq.y;                           \
        wr[q * 4 + 2] = wq.z; wr[q * 4 + 3] = wq.w;                           \
      }                                                                       \
      float xk = acc_t[k] + wr[k];                                            \
      float s  = __builtin_amdgcn_rcpf(                                       \
          1.f + __builtin_amdgcn_exp2f(xk * -1.44269504088896341f));          \
      acc_t[k] = s;                                                           \
      _Pragma("unroll")                                                       \
      for (int c = k + 1; c < 16; ++c)                                        \
        acc_t[c] = __builtin_fmaf(s, wr[c], acc_t[c]);                        \
    }                                                                         \
    if ((b) == NBLK - 1) {                                                    \
      const size_t orow = (size_t)(slab_off + rb + r16) * OUT_DIM;            \
      _Pragma("unroll")                                                       \
      for (int i = 0; i < 4; ++i) {                                           \
        float a01 = (g & 1) ? acc_t[4 + i] : acc_t[i];                        \
        float a23 = (g & 1) ? acc_t[12 + i] : acc_t[8 + i];                   \
        float ov  = (g & 2) ? a23 : a01;                                      \
        int oc = 4 * g + i;                                                   \
        int mi = NMID - OUT_DIM + oc;                                         \
        out[orow + oc] = (ov + bias[mi]) * (float)ex[mi];                     \
      }                                                                       \
    } else {                                                                  \
      float pv[8];                                                            \
      _Pragma("unroll")                                                       \
      for (int j = 0; j < 8; ++j)                                             \
        pv[j] = (g & 1) ? acc_t[8 + j] : acc_t[j];                            \
      uint4 packed;                                                           \
      CVT_PK(packed.x, pv[0], pv[1]);                                         \
      CVT_PK(packed.y, pv[2], pv[3]);                                         \
      CVT_PK(packed.z, pv[4], pv[5]);                                         \
      CVT_PK(packed.w, pv[6], pv[7]);                                         \
      const bool part = ((g >> 1) == ((b) & 1));                              \
      const int cml = ((b) >> 1) & 7;                                         \
      if ((b) < 16) {                                                         \
        _Pragma("unroll")                                                     \
        for (int c2 = 0; c2 < 8; ++c2)                                        \
          if (c2 == cml) { if (part) sfrag[c2] = packed; }                    \
      } else if ((b) < 32) {                                                  \
        _Pragma("unroll")                                                     \
        for (int c2 = 0; c2 < 8; ++c2)                                        \
          if (c2 == cml) { if (part) sfrag[8 + c2] = packed; }                \
      } else {                                                                \
        _Pragma("unroll")                                                     \
        for (int c2 = 0; c2 < 8; ++c2)                                        \
          if (c2 == cml) { if (part) sfrag[16 + c2] = packed; }               \
      }                                                                       \
    }                                                                         \
    __syncthreads();                                                          \
  } while (0)

  // prologue: wtri for block 0 (block 0 has no B-chunks)
  if (wv == 0)
    *(float4*)&wtriF[0][l * 4] = *(const float4*)(wpk + l * 4);
  __syncthreads();

  #pragma clang loop unroll(disable)
  for (int b = 0; b < NBLK; b += 2) {
    BODY(b, 0);
    if (b + 1 < NBLK) BODY(b + 1, 1);
  }
#undef BODY
#undef CHUNK
#undef STAGE_B
}

// ---------------------------------------------------------------------------
extern "C" void kernel_launch(void* const* d_in, const int* in_sizes, int n_in,
                              void* d_out, int out_size, void* d_ws, size_t ws_size,
                              hipStream_t stream) {
  const float* x      = (const float*)d_in[0];
  const float* weight = (const float*)d_in[1];
  const float* bias   = (const float*)d_in[2];
  const int*   conn   = (const int*)d_in[3];
  const int*   ex     = (const int*)d_in[4];

  char* ws = (char*)d_ws;
  size_t off = 0;
  unsigned short* effX = (unsigned short*)(ws + off); off += (size_t)NMID * INPUT_DIM * 2;
  unsigned short* effM = (unsigned short*)(ws + off); off += (size_t)NMID * MROW * 2;
  float*          cvec = (float*)(ws + off);          off += (size_t)NMID * 4;
  float*          wpk  = (float*)(ws + off);          off += (size_t)NBLK * 256 * 4;
  off = (off + 255) & ~(size_t)255;
  const size_t fixed = off;

  // Pt slab sizing (bytes per slab = slabsz/16 * NBLK * 256 * 2)
  int nslabs = 1;
  while (nslabs < 16 &&
         fixed + (size_t)(BATCH / nslabs) * NBLK * 16 * 2 > ws_size)
    nslabs <<= 1;
  const int slabsz = BATCH / nslabs;
  unsigned short* Pt = (unsigned short*)(ws + fixed);

  prep_efft<<<dim3(16, 13), 256, 0, stream>>>(weight, conn, ex, effX, effM);
  prep_cvec<<<dim3(NMID), 64, 0, stream>>>(effM, weight, conn, ex, bias, cvec);
  prep_wpack<<<dim3(NBLK), 256, 0, stream>>>(weight, conn, ex, cvec, wpk);

  for (int s = 0; s < nslabs; ++s) {
    pgemm<<<dim3(slabsz / 64), 256, 0, stream>>>(
        x, effX, Pt, s * slabsz, slabsz);
    net_main<<<dim3(slabsz / 64), 256, 0, stream>>>(
        Pt, effM, wpk, bias, ex, (float*)d_out, s * slabsz, slabsz);
  }
}

// Round 10
// 262.494 us; speedup vs baseline: 2.2896x; 1.1870x over previous
//
#include <hip/hip_runtime.h>
#include <cstdint>
#include <cstddef>

#define INPUT_DIM 256
#define OUT_DIM   16
#define NMID      784     // middle nodes
#define NNODE     1040
#define MROW      768     // effM row length (middle cols; cols >=768 are in-block only)
#define KB        16      // node block size
#define NBLK      49      // 784 / 16
#define NMCH      24      // middle-state chunks of 32 k-elems (768/32)
#define BATCH     32768
#define UNITW     520     // ushorts per 2-row LDS unit (1040 B)
#define XROW      264     // pgemm LDS x row stride (528 B)

typedef float f32x4 __attribute__((ext_vector_type(4)));
typedef __bf16 bf16x8 __attribute__((ext_vector_type(8)));

#define GLL16(gp, lp)                                                        \
  __builtin_amdgcn_global_load_lds(                                          \
      (const __attribute__((address_space(1))) unsigned int*)(gp),           \
      (__attribute__((address_space(3))) unsigned int*)(lp), 16, 0, 0)

static __device__ __forceinline__ unsigned int f2bf(float f) {
  unsigned int u = __builtin_bit_cast(unsigned int, f);
  u += 0x7fffu + ((u >> 16) & 1u);   // round-to-nearest-even
  return u >> 16;
}
static __device__ __forceinline__ float bf2f(unsigned short h) {
  unsigned int u = ((unsigned int)h) << 16;
  return __builtin_bit_cast(float, u);
}
static __device__ __forceinline__ float bflo(unsigned int w) {
  return __builtin_bit_cast(float, w << 16);
}
static __device__ __forceinline__ float bfhi(unsigned int w) {
  return __builtin_bit_cast(float, w & 0xffff0000u);
}

// ---------------------------------------------------------------------------
// Prep 1: split masked weights into
//   effX[i][k]  = w[k][i]*conn[k][i]              (k<256, always causal), bf16
//   effM[i][jm] = w[256+jm][i]*conn*ex[jm]*(jm<i) (jm<768; >=768 is in-block)
// ---------------------------------------------------------------------------
__global__ __launch_bounds__(256) void prep_efft(
    const float* __restrict__ w, const int* __restrict__ conn,
    const int* __restrict__ ex, unsigned short* __restrict__ effX,
    unsigned short* __restrict__ effM) {
  __shared__ unsigned short tile[64][66];
  const int j0 = blockIdx.x * 64;
  const int i0 = blockIdx.y * 64;
  const int tx = threadIdx.x & 63;   // i offset
  const int ty = threadIdx.x >> 6;   // j sub-row
  const int i  = i0 + tx;
  for (int t = 0; t < 16; ++t) {
    int j = j0 + t * 4 + ty;
    float v = 0.f;
    if (j < NNODE && i < NMID && j < INPUT_DIM + i) {
      float e = (j >= INPUT_DIM) ? (float)ex[j - INPUT_DIM] : 1.f;
      v = w[(size_t)j * NMID + i] * (float)conn[(size_t)j * NMID + i] * e;
    }
    tile[t * 4 + ty][tx] = (unsigned short)f2bf(v);
  }
  __syncthreads();
  const int i_loc = threadIdx.x >> 2;
  const int jq    = threadIdx.x & 3;
  const int iw    = i0 + i_loc;
  const int jbase = j0 + jq * 16;
  if (iw < NMID) {
    if (jbase + 16 <= INPUT_DIM) {
      #pragma unroll
      for (int c = 0; c < 16; ++c)
        effX[(size_t)iw * INPUT_DIM + jbase + c] = tile[jq * 16 + c][i_loc];
    } else if (jbase >= INPUT_DIM && (jbase - INPUT_DIM + 16) <= MROW) {
      #pragma unroll
      for (int c = 0; c < 16; ++c)
        effM[(size_t)iw * MROW + (jbase - INPUT_DIM) + c] =
            tile[jq * 16 + c][i_loc];
    }
  }
}

// ---------------------------------------------------------------------------
// Prep 2: cvec[i] = sum_jm effweight[jm->i] * bias[jm]  (bias folded constant)
// ---------------------------------------------------------------------------
__global__ __launch_bounds__(64) void prep_cvec(
    const unsigned short* __restrict__ effM, const float* __restrict__ w,
    const int* __restrict__ conn, const int* __restrict__ ex,
    const float* __restrict__ bias, float* __restrict__ cvec) {
  const int i = blockIdx.x;
  const int l = threadIdx.x;
  float s = 0.f;
  for (int jm = l; jm < MROW; jm += 64)
    s += bf2f(effM[(size_t)i * MROW + jm]) * bias[jm];
  {
    int jm = MROW + l;                 // valid only 768..783
    if (jm < NMID && jm < i) {
      size_t idx = (size_t)(INPUT_DIM + jm) * NMID + i;
      s += w[idx] * (float)conn[idx] * (float)ex[jm] * bias[jm];
    }
  }
  for (int off = 32; off; off >>= 1) s += __shfl_down(s, off, 64);
  if (l == 0) cvec[i] = s;
}

// ---------------------------------------------------------------------------
// Prep 3: wpk[b][k][c] (bf16): k<c -> w[256+16b+k][16b+c]*conn*ex[16b+k]
//                              k==c -> cvec[16b+k]; k>c -> 0
// ---------------------------------------------------------------------------
__global__ __launch_bounds__(256) void prep_wpack(
    const float* __restrict__ w, const int* __restrict__ conn,
    const int* __restrict__ ex, const float* __restrict__ cvec,
    unsigned short* __restrict__ wpk) {
  const int b = blockIdx.x;
  const int k = threadIdx.x >> 4;
  const int c = threadIdx.x & 15;
  const int src = KB * b + k;
  const int dst = KB * b + c;
  float v = 0.f;
  if (k < c) {
    size_t idx = (size_t)(INPUT_DIM + src) * NMID + dst;
    v = w[idx] * (float)conn[idx] * (float)ex[src];
  } else if (k == c) {
    v = cvec[src];
  }
  wpk[b * 256 + k * 16 + c] = (unsigned short)f2bf(v);
}

// ---------------------------------------------------------------------------
// P-GEMM: Pt[node][batch_local] = sum_k effX[node][k] * x[batch][k], bf16 out.
// Block = 256 thr; stage x[64][256] bf16 to LDS once; waves then loop
// node-blocks independently (no further barriers).
// ---------------------------------------------------------------------------
__global__ __launch_bounds__(256)
__attribute__((amdgpu_waves_per_eu(2, 4))) void pgemm(
    const float* __restrict__ x, const unsigned short* __restrict__ effX,
    unsigned short* __restrict__ Pt, int slab_off, int slabsz) {
  __shared__ __align__(16) unsigned short xs[64][XROW];   // 33792 B

  const int tid = threadIdx.x;
  const int l   = tid & 63;
  const int wv  = tid >> 6;
  const int g   = l >> 4;
  const int r16 = l & 15;
  const int bb  = blockIdx.x * 64;          // slab-local batch base

  // ---- stage x tile as bf16 ----
  {
    const int row = tid >> 2;
    const int q   = tid & 3;
    const float* xr = x + (size_t)(slab_off + bb + row) * INPUT_DIM + q * 64;
    unsigned short* xd = &xs[row][q * 64];
    #pragma unroll
    for (int i = 0; i < 16; ++i) {
      float4 v = *(const float4*)(xr + 4 * i);
      uint2 u;
      u.x = f2bf(v.x) | (f2bf(v.y) << 16);
      u.y = f2bf(v.z) | (f2bf(v.w) << 16);
      *(uint2*)(xd + 4 * i) = u;
    }
  }
  __syncthreads();

  for (int nb = wv; nb < NBLK; nb += 4) {
    const unsigned short* ap =
        effX + (size_t)(nb * 16 + r16) * INPUT_DIM + 8 * g;
    uint4 a[8];
    #pragma unroll
    for (int c = 0; c < 8; ++c) a[c] = *(const uint4*)(ap + 32 * c);

    #pragma unroll
    for (int s = 0; s < 4; ++s) {
      f32x4 acc = {0.f, 0.f, 0.f, 0.f};
      #pragma unroll
      for (int c = 0; c < 8; ++c) {
        uint4 braw = *(const uint4*)&xs[s * 16 + r16][32 * c + 8 * g];
        acc = __builtin_amdgcn_mfma_f32_16x16x32_bf16(
            __builtin_bit_cast(bf16x8, a[c]), __builtin_bit_cast(bf16x8, braw),
            acc, 0, 0, 0);
      }
      // C[m=node0+4g+i][n=brow]
      #pragma unroll
      for (int i = 0; i < 4; ++i)
        Pt[(size_t)(nb * 16 + 4 * g + i) * slabsz + bb + s * 16 + r16] =
            (unsigned short)f2bf(acc[i]);
    }
  }
}

// ---------------------------------------------------------------------------
// Main sequential kernel (r7 structure). Wave = 16 batch rows, middle state
// in regs (uint4 sfrag[24], MFMA-A layout). Per block:
//   MFMA over prior middle chunks (B from swizzled LDS, global_load_lds
//   staged, double-buffered) -> add Pt -> LDS transpose -> in-reg triangular
//   solve -> pack into owning fragment reg. One barrier per block.
// NEW vs r7: triangular weights come from GLOBAL (8 B/lane, L2-resident,
// issued at block top) and are extracted per-row via v_readlane with
// compile-time lane indices -> SGPR weights, SALU unpack, zero LDS traffic.
// Removes the 32 redundant b128 wtri reads/wave/block (top LDS-pipe stream).
// ---------------------------------------------------------------------------
__global__ __launch_bounds__(256)
__attribute__((amdgpu_waves_per_eu(2, 2))) void net_main(
    const unsigned short* __restrict__ Pt,
    const unsigned short* __restrict__ effM,
    const unsigned short* __restrict__ wpk,
    const float* __restrict__ bias, const int* __restrict__ ex,
    float* __restrict__ out, int slab_off, int slabsz) {
  __shared__ __align__(16) unsigned short Bs[2][3][8][UNITW];  // 49920 B
  __shared__ float scrS[4][320];                               //  5120 B

  const int tid = threadIdx.x;
  const int l   = tid & 63;
  const int wv  = tid >> 6;
  const int g   = l >> 4;
  const int r16 = l & 15;
  const int rb  = (blockIdx.x * 4 + wv) * 16;   // slab-local batch base
  float* myscr = scrS[wv];

  uint4 sfrag[NMCH];
  #pragma unroll
  for (int c = 0; c < NMCH; ++c) {
    uint4 z; z.x = z.y = z.z = z.w = 0u;
    sfrag[c] = z;
  }

#define STAGE_B(nb, t)                                                        \
  {                                                                           \
    _Pragma("unroll")                                                         \
    for (int q_ = 0; q_ < 2; ++q_) {                                          \
      const int rp_ = wv + 4 * q_;           /* unit 0..7 */                  \
      const int r_  = 2 * rp_ + (l >> 5);    /* B-row 0..15 */                \
      const int cl_ = (l & 31) ^ (r_ & 7);                                    \
      const unsigned short* gs_ =                                             \
          effM + (size_t)(16 * (t) + r_) * MROW + cl_ * 8;                    \
      GLL16(gs_, &Bs[nb][0][rp_][0]);                                         \
      if ((t) >= 17) GLL16(gs_ + 256, &Bs[nb][1][rp_][0]);                    \
      if ((t) >= 33) GLL16(gs_ + 512, &Bs[nb][2][rp_][0]);                    \
    }                                                                         \
  }

  // ---- prologue: stage block 0's B ----
  STAGE_B(0, 0);
  __syncthreads();

  for (int b = 0; b < NBLK; ++b) {
    const int cur = b & 1;

    if (b + 1 < NBLK) {
      STAGE_B(cur ^ 1, b + 1);
    }

    // Triangular-weight slice for THIS block: lane l holds wpk ushorts
    // [b*256 + 4l .. 4l+3] (row l>>2, cols (l&3)*4..+3). 512 B from L2,
    // same for every wave; latency hides under the GEMM below.
    const uint2 wl = *(const uint2*)(wpk + b * 256 + l * 4);

    // Pt (x contribution): issued here, consumed after the GEMM.
    uint2 praw = *(const uint2*)(Pt + (size_t)(KB * b + r16) * slabsz +
                                 rb + 4 * g);

    // ---- GEMM over prior middle chunks (phase-guarded straight lines) ----
    f32x4 ac0 = {0.f, 0.f, 0.f, 0.f}, ac1 = ac0, ac2 = ac0, ac3 = ac0;
#define CHUNK(c)                                                              \
  {                                                                           \
    const int pp_ = (c) >> 3, cc_ = (c) & 7;                                  \
    uint4 braw = *(const uint4*)&Bs[cur][pp_][r16 >> 1]                       \
        [(r16 & 1) * 256 + (((cc_ * 4 + g) ^ (r16 & 7)) * 8)];                \
    f32x4& a_ = ((c) & 3) == 0 ? ac0 : ((c) & 3) == 1 ? ac1                   \
               : ((c) & 3) == 2 ? ac2 : ac3;                                  \
    a_ = __builtin_amdgcn_mfma_f32_16x16x32_bf16(                             \
        __builtin_bit_cast(bf16x8, sfrag[(c)]),                               \
        __builtin_bit_cast(bf16x8, braw), a_, 0, 0, 0);                       \
  }
    if (b >= 1) {
      CHUNK(0) CHUNK(1) CHUNK(2) CHUNK(3)
      CHUNK(4) CHUNK(5) CHUNK(6) CHUNK(7)
    }
    if (b >= 17) {
      CHUNK(8) CHUNK(9) CHUNK(10) CHUNK(11)
      CHUNK(12) CHUNK(13) CHUNK(14) CHUNK(15)
    }
    if (b >= 33) {
      CHUNK(16) CHUNK(17) CHUNK(18) CHUNK(19)
      CHUNK(20) CHUNK(21) CHUNK(22) CHUNK(23)
    }
#undef CHUNK
    f32x4 accsum = (ac0 + ac1) + (ac2 + ac3);
    accsum[0] += bflo(praw.x);
    accsum[1] += bfhi(praw.x);
    accsum[2] += bflo(praw.y);
    accsum[3] += bfhi(praw.y);

    // ---- transpose via per-wave LDS scratch (C-layout -> row-per-lane) ----
    #pragma unroll
    for (int i = 0; i < 4; ++i)
      myscr[(4 * g + i) * 20 + r16] = accsum[i];
    float acc_t[16];
    #pragma unroll
    for (int c = 0; c < 16; ++c)
      acc_t[c] = myscr[r16 * 20 + c];

    // ---- triangular solve: weights via readlane (SGPR), no LDS traffic ----
    const int wlx = (int)wl.x, wly = (int)wl.y;
    #pragma unroll
    for (int k = 0; k < 16; ++k) {
      // row k, columns k..15: ushort 16k+c lives in lane 4k+(c>>2),
      // word (c>>1)&1, half c&1. readlane lane indices are compile-time.
      float wcol[16];
      #pragma unroll
      for (int p = k >> 1; p < 8; ++p) {
        const int lane = 4 * k + (p >> 1);
        int raw = (p & 1) ? __builtin_amdgcn_readlane(wly, lane)
                          : __builtin_amdgcn_readlane(wlx, lane);
        wcol[2 * p]     = bflo((unsigned int)raw);
        wcol[2 * p + 1] = bfhi((unsigned int)raw);
      }
      float xk = acc_t[k] + wcol[k];              // diagonal carries cvec
      float s  = __builtin_amdgcn_rcpf(
          1.f + __builtin_amdgcn_exp2f(xk * -1.44269504088896341f));
      acc_t[k] = s;
      #pragma unroll
      for (int c = k + 1; c < 16; ++c)
        acc_t[c] = __builtin_fmaf(s, wcol[c], acc_t[c]);
    }

    if (b == NBLK - 1) {
      const size_t orow = (size_t)(slab_off + rb + r16) * OUT_DIM;
      #pragma unroll
      for (int i = 0; i < 4; ++i) {
        int oc = 4 * g + i;
        int mi = NMID - OUT_DIM + oc;
        out[orow + oc] = (acc_t[oc] + bias[mi]) * (float)ex[mi];
      }
    } else {
      // pack the 16 new values into the owning middle-chunk register;
      // phase-local 8-iter guard (cm = b>>1 = base + ((b>>1)&7))
      const int cml = (b >> 1) & 7;
      const int vb = 8 * (g & 1);
      uint4 packed;
      packed.x = f2bf(acc_t[vb + 0]) | (f2bf(acc_t[vb + 1]) << 16);
      packed.y = f2bf(acc_t[vb + 2]) | (f2bf(acc_t[vb + 3]) << 16);
      packed.z = f2bf(acc_t[vb + 4]) | (f2bf(acc_t[vb + 5]) << 16);
      packed.w = f2bf(acc_t[vb + 6]) | (f2bf(acc_t[vb + 7]) << 16);
      const bool part = ((g >> 1) == (b & 1));
#define PACKW(base)                                                           \
  {                                                                           \
    _Pragma("unroll")                                                         \
    for (int c2 = 0; c2 < 8; ++c2)                                            \
      if (c2 == cml) {                                                        \
        if (part) sfrag[(base) + c2] = packed;                                \
      }                                                                       \
  }
      if (b < 16) {
        PACKW(0)
      } else if (b < 32) {
        PACKW(8)
      } else {
        PACKW(16)
      }
#undef PACKW
    }

    __syncthreads();   // publish staged B; prior LDS reads done
  }
#undef STAGE_B
}

// ---------------------------------------------------------------------------
extern "C" void kernel_launch(void* const* d_in, const int* in_sizes, int n_in,
                              void* d_out, int out_size, void* d_ws, size_t ws_size,
                              hipStream_t stream) {
  const float* x      = (const float*)d_in[0];
  const float* weight = (const float*)d_in[1];
  const float* bias   = (const float*)d_in[2];
  const int*   conn   = (const int*)d_in[3];
  const int*   ex     = (const int*)d_in[4];

  char* ws = (char*)d_ws;
  size_t off = 0;
  unsigned short* effX = (unsigned short*)(ws + off); off += (size_t)NMID * INPUT_DIM * 2;
  unsigned short* effM = (unsigned short*)(ws + off); off += (size_t)NMID * MROW * 2;
  float*          cvec = (float*)(ws + off);          off += (size_t)NMID * 4;
  unsigned short* wpk  = (unsigned short*)(ws + off); off += (size_t)NBLK * 256 * 2;
  off = (off + 255) & ~(size_t)255;
  const size_t fixed = off;

  // Pt slab sizing: smallest power-of-two slab count that fits ws.
  int nslabs = 1;
  while (nslabs < 16 &&
         fixed + (size_t)NMID * (BATCH / nslabs) * 2 > ws_size)
    nslabs <<= 1;
  const int slabsz = BATCH / nslabs;
  unsigned short* Pt = (unsigned short*)(ws + fixed);

  prep_efft<<<dim3(16, 13), 256, 0, stream>>>(weight, conn, ex, effX, effM);
  prep_cvec<<<dim3(NMID), 64, 0, stream>>>(effM, weight, conn, ex, bias, cvec);
  prep_wpack<<<dim3(NBLK), 256, 0, stream>>>(weight, conn, ex, cvec, wpk);

  for (int s = 0; s < nslabs; ++s) {
    pgemm<<<dim3(slabsz / 64), 256, 0, stream>>>(
        x, effX, Pt, s * slabsz, slabsz);
    net_main<<<dim3(slabsz / 64), 256, 0, stream>>>(
        Pt, effM, wpk, bias, ex, (float*)d_out, s * slabsz, slabsz);
  }
}

// Round 11
// 229.049 us; speedup vs baseline: 2.6239x; 1.1460x over previous
//
#include <hip/hip_runtime.h>
#include <cstdint>
#include <cstddef>

#define INPUT_DIM 256
#define OUT_DIM   16
#define NMID      784     // middle nodes
#define NNODE     1040
#define MROW      768     // effM row length (middle cols; cols >=768 are in-block only)
#define KB        16      // node block size
#define NBLK      49      // 784 / 16
#define NMCH      24      // middle-state chunks of 32 k-elems (768/32)
#define BATCH     32768
#define UNITW     520     // ushorts per 2-row LDS unit (1040 B)
#define XROW      264     // pgemm LDS x row stride (528 B)

typedef float f32x4 __attribute__((ext_vector_type(4)));
typedef __bf16 bf16x8 __attribute__((ext_vector_type(8)));

#define GLL16(gp, lp)                                                        \
  __builtin_amdgcn_global_load_lds(                                          \
      (const __attribute__((address_space(1))) unsigned int*)(gp),           \
      (__attribute__((address_space(3))) unsigned int*)(lp), 16, 0, 0)

static __device__ __forceinline__ unsigned int f2bf(float f) {
  unsigned int u = __builtin_bit_cast(unsigned int, f);
  u += 0x7fffu + ((u >> 16) & 1u);   // round-to-nearest-even
  return u >> 16;
}
static __device__ __forceinline__ float bf2f(unsigned short h) {
  unsigned int u = ((unsigned int)h) << 16;
  return __builtin_bit_cast(float, u);
}
static __device__ __forceinline__ float bflo(unsigned int w) {
  return __builtin_bit_cast(float, w << 16);
}
static __device__ __forceinline__ float bfhi(unsigned int w) {
  return __builtin_bit_cast(float, w & 0xffff0000u);
}

// In-register 16-node triangular solve; wt = bf16 16x16 tile (broadcast LDS
// reads, off the dependency chain). Diagonal carries the folded cvec.
static __device__ __forceinline__ void solve16(float* acc_t,
                                               const unsigned short* wt) {
  #pragma unroll
  for (int k = 0; k < 16; ++k) {
    const uint4 w0 = *(const uint4*)&wt[k * 16];
    const uint4 w1 = *(const uint4*)&wt[k * 16 + 8];
    const unsigned int wd[8] = {w0.x, w0.y, w0.z, w0.w,
                                w1.x, w1.y, w1.z, w1.w};
    float xk = acc_t[k] + ((k & 1) ? bfhi(wd[k >> 1]) : bflo(wd[k >> 1]));
    float s  = __builtin_amdgcn_rcpf(
        1.f + __builtin_amdgcn_exp2f(xk * -1.44269504088896341f));
    acc_t[k] = s;
    #pragma unroll
    for (int c = k + 1; c < 16; ++c) {
      float wc = (c & 1) ? bfhi(wd[c >> 1]) : bflo(wd[c >> 1]);
      acc_t[c] = __builtin_fmaf(s, wc, acc_t[c]);
    }
  }
}

// ---------------------------------------------------------------------------
// Prep 1: split masked weights into
//   effX[i][k]  = w[k][i]*conn[k][i]              (k<256, always causal), bf16
//   effM[i][jm] = w[256+jm][i]*conn*ex[jm]*(jm<i) (jm<768; >=768 is in-block)
// ---------------------------------------------------------------------------
__global__ __launch_bounds__(256) void prep_efft(
    const float* __restrict__ w, const int* __restrict__ conn,
    const int* __restrict__ ex, unsigned short* __restrict__ effX,
    unsigned short* __restrict__ effM) {
  __shared__ unsigned short tile[64][66];
  const int j0 = blockIdx.x * 64;
  const int i0 = blockIdx.y * 64;
  const int tx = threadIdx.x & 63;   // i offset
  const int ty = threadIdx.x >> 6;   // j sub-row
  const int i  = i0 + tx;
  for (int t = 0; t < 16; ++t) {
    int j = j0 + t * 4 + ty;
    float v = 0.f;
    if (j < NNODE && i < NMID && j < INPUT_DIM + i) {
      float e = (j >= INPUT_DIM) ? (float)ex[j - INPUT_DIM] : 1.f;
      v = w[(size_t)j * NMID + i] * (float)conn[(size_t)j * NMID + i] * e;
    }
    tile[t * 4 + ty][tx] = (unsigned short)f2bf(v);
  }
  __syncthreads();
  const int i_loc = threadIdx.x >> 2;
  const int jq    = threadIdx.x & 3;
  const int iw    = i0 + i_loc;
  const int jbase = j0 + jq * 16;
  if (iw < NMID) {
    if (jbase + 16 <= INPUT_DIM) {
      #pragma unroll
      for (int c = 0; c < 16; ++c)
        effX[(size_t)iw * INPUT_DIM + jbase + c] = tile[jq * 16 + c][i_loc];
    } else if (jbase >= INPUT_DIM && (jbase - INPUT_DIM + 16) <= MROW) {
      #pragma unroll
      for (int c = 0; c < 16; ++c)
        effM[(size_t)iw * MROW + (jbase - INPUT_DIM) + c] =
            tile[jq * 16 + c][i_loc];
    }
  }
}

// ---------------------------------------------------------------------------
// Prep 2: cvec[i] = sum_jm effweight[jm->i] * bias[jm]  (bias folded constant)
// ---------------------------------------------------------------------------
__global__ __launch_bounds__(64) void prep_cvec(
    const unsigned short* __restrict__ effM, const float* __restrict__ w,
    const int* __restrict__ conn, const int* __restrict__ ex,
    const float* __restrict__ bias, float* __restrict__ cvec) {
  const int i = blockIdx.x;
  const int l = threadIdx.x;
  float s = 0.f;
  for (int jm = l; jm < MROW; jm += 64)
    s += bf2f(effM[(size_t)i * MROW + jm]) * bias[jm];
  {
    int jm = MROW + l;                 // valid only 768..783
    if (jm < NMID && jm < i) {
      size_t idx = (size_t)(INPUT_DIM + jm) * NMID + i;
      s += w[idx] * (float)conn[idx] * (float)ex[jm] * bias[jm];
    }
  }
  for (int off = 32; off; off >>= 1) s += __shfl_down(s, off, 64);
  if (l == 0) cvec[i] = s;
}

// ---------------------------------------------------------------------------
// Prep 3: wpk[b][k][c] (bf16): k<c -> w[256+16b+k][16b+c]*conn*ex[16b+k]
//                              k==c -> cvec[16b+k]; k>c -> 0
// ---------------------------------------------------------------------------
__global__ __launch_bounds__(256) void prep_wpack(
    const float* __restrict__ w, const int* __restrict__ conn,
    const int* __restrict__ ex, const float* __restrict__ cvec,
    unsigned short* __restrict__ wpk) {
  const int b = blockIdx.x;
  const int k = threadIdx.x >> 4;
  const int c = threadIdx.x & 15;
  const int src = KB * b + k;
  const int dst = KB * b + c;
  float v = 0.f;
  if (k < c) {
    size_t idx = (size_t)(INPUT_DIM + src) * NMID + dst;
    v = w[idx] * (float)conn[idx] * (float)ex[src];
  } else if (k == c) {
    v = cvec[src];
  }
  wpk[b * 256 + k * 16 + c] = (unsigned short)f2bf(v);
}

// ---------------------------------------------------------------------------
// P-GEMM: Pt[node][batch_local] = sum_k effX[node][k] * x[batch][k], bf16 out.
// ---------------------------------------------------------------------------
__global__ __launch_bounds__(256)
__attribute__((amdgpu_waves_per_eu(2, 4))) void pgemm(
    const float* __restrict__ x, const unsigned short* __restrict__ effX,
    unsigned short* __restrict__ Pt, int slab_off, int slabsz) {
  __shared__ __align__(16) unsigned short xs[64][XROW];   // 33792 B

  const int tid = threadIdx.x;
  const int l   = tid & 63;
  const int wv  = tid >> 6;
  const int g   = l >> 4;
  const int r16 = l & 15;
  const int bb  = blockIdx.x * 64;          // slab-local batch base

  {
    const int row = tid >> 2;
    const int q   = tid & 3;
    const float* xr = x + (size_t)(slab_off + bb + row) * INPUT_DIM + q * 64;
    unsigned short* xd = &xs[row][q * 64];
    #pragma unroll
    for (int i = 0; i < 16; ++i) {
      float4 v = *(const float4*)(xr + 4 * i);
      uint2 u;
      u.x = f2bf(v.x) | (f2bf(v.y) << 16);
      u.y = f2bf(v.z) | (f2bf(v.w) << 16);
      *(uint2*)(xd + 4 * i) = u;
    }
  }
  __syncthreads();

  for (int nb = wv; nb < NBLK; nb += 4) {
    const unsigned short* ap =
        effX + (size_t)(nb * 16 + r16) * INPUT_DIM + 8 * g;
    uint4 a[8];
    #pragma unroll
    for (int c = 0; c < 8; ++c) a[c] = *(const uint4*)(ap + 32 * c);

    #pragma unroll
    for (int s = 0; s < 4; ++s) {
      f32x4 acc = {0.f, 0.f, 0.f, 0.f};
      #pragma unroll
      for (int c = 0; c < 8; ++c) {
        uint4 braw = *(const uint4*)&xs[s * 16 + r16][32 * c + 8 * g];
        acc = __builtin_amdgcn_mfma_f32_16x16x32_bf16(
            __builtin_bit_cast(bf16x8, a[c]), __builtin_bit_cast(bf16x8, braw),
            acc, 0, 0, 0);
      }
      #pragma unroll
      for (int i = 0; i < 4; ++i)
        Pt[(size_t)(nb * 16 + 4 * g + i) * slabsz + bb + s * 16 + r16] =
            (unsigned short)f2bf(acc[i]);
    }
  }
}

// ---------------------------------------------------------------------------
// Main sequential kernel with DEFERRED-SOLVE pipelining.
// Per iteration b (1..48):
//   STAGE(b+1) -> full pre-pack GEMM(b) (chunk cstar's b-1 half is still
//   zero -> contributes 0) -> solve block b-1 (data from scr, ready at iter
//   start; overlaps the GEMM streams) -> pack -> ONE correction MFMA with
//   A = (part ? packed : 0) adding block b-1's contribution -> +Pt ->
//   scr write -> barrier. Solve's serial VALU chain hides under MFMA/LDS.
// wtri: bf16 broadcast reads from a 3-slot LDS ring (deferral-safe).
// waves_per_eu(2,2): proven no-spill point (r7); >2 spills sfrag (r5/r8).
// ---------------------------------------------------------------------------
__global__ __launch_bounds__(256)
__attribute__((amdgpu_waves_per_eu(2, 2))) void net_main(
    const unsigned short* __restrict__ Pt,
    const unsigned short* __restrict__ effM,
    const unsigned short* __restrict__ wpk,
    const float* __restrict__ bias, const int* __restrict__ ex,
    float* __restrict__ out, int slab_off, int slabsz) {
  __shared__ __align__(16) unsigned short Bs[2][3][8][UNITW];  // 49920 B
  __shared__ __align__(16) unsigned short wtriL[3][256];       //  1536 B
  __shared__ float scrS[4][320];                               //  5120 B

  const int tid = threadIdx.x;
  const int l   = tid & 63;
  const int wv  = tid >> 6;
  const int g   = l >> 4;
  const int r16 = l & 15;
  const int rb  = (blockIdx.x * 4 + wv) * 16;   // slab-local batch base
  float* myscr = scrS[wv];

  uint4 sfrag[NMCH];
  #pragma unroll
  for (int c = 0; c < NMCH; ++c) {
    uint4 z; z.x = z.y = z.z = z.w = 0u;
    sfrag[c] = z;
  }

#define STAGE_B(nb, t)                                                        \
  {                                                                           \
    _Pragma("unroll")                                                         \
    for (int q_ = 0; q_ < 2; ++q_) {                                          \
      const int rp_ = wv + 4 * q_;           /* unit 0..7 */                  \
      const int r_  = 2 * rp_ + (l >> 5);    /* B-row 0..15 */                \
      const int cl_ = (l & 31) ^ (r_ & 7);                                    \
      const unsigned short* gs_ =                                             \
          effM + (size_t)(16 * (t) + r_) * MROW + cl_ * 8;                    \
      GLL16(gs_, &Bs[nb][0][rp_][0]);                                         \
      if ((t) >= 17) GLL16(gs_ + 256, &Bs[nb][1][rp_][0]);                    \
      if ((t) >= 33) GLL16(gs_ + 512, &Bs[nb][2][rp_][0]);                    \
    }                                                                         \
  }
#define STAGE_W(t)                                                            \
  if (wv == 0)                                                                \
    *(uint2*)&wtriL[(t) % 3][l * 4] = *(const uint2*)(wpk + (t) * 256 + l * 4);

  // ---- iteration 0 (block 0): no GEMM, no pending solve ----
  STAGE_W(0);
  STAGE_B(1, 1);
  STAGE_W(1);
  {
    uint2 praw = *(const uint2*)(Pt + (size_t)r16 * slabsz + rb + 4 * g);
    myscr[(4 * g + 0) * 20 + r16] = bflo(praw.x);
    myscr[(4 * g + 1) * 20 + r16] = bfhi(praw.x);
    myscr[(4 * g + 2) * 20 + r16] = bflo(praw.y);
    myscr[(4 * g + 3) * 20 + r16] = bfhi(praw.y);
  }
  __syncthreads();

  for (int b = 1; b < NBLK; ++b) {
    const int cur = b & 1;
    const int pb  = b - 1;            // pending (deferred-solve) block
    const int cstar = pb >> 1;        // chunk that receives block pb

    if (b + 1 < NBLK) {
      STAGE_B(cur ^ 1, b + 1);
      STAGE_W(b + 1);
    }

    // Pt (x contribution) for block b: issue early, consume late.
    uint2 praw = *(const uint2*)(Pt + (size_t)(KB * b + r16) * slabsz +
                                 rb + 4 * g);

    // ---- pre-pack GEMM(b): full phase-guarded chunks. Chunk cstar's
    //      pb-half is still zero in sfrag -> contributes 0 (no skip). ----
    f32x4 ac0 = {0.f, 0.f, 0.f, 0.f}, ac1 = ac0, ac2 = ac0, ac3 = ac0;
#define CHUNK(c)                                                              \
  {                                                                           \
    const int pp_ = (c) >> 3, cc_ = (c) & 7;                                  \
    uint4 braw = *(const uint4*)&Bs[cur][pp_][r16 >> 1]                       \
        [(r16 & 1) * 256 + (((cc_ * 4 + g) ^ (r16 & 7)) * 8)];                \
    f32x4& a_ = ((c) & 3) == 0 ? ac0 : ((c) & 3) == 1 ? ac1                   \
               : ((c) & 3) == 2 ? ac2 : ac3;                                  \
    a_ = __builtin_amdgcn_mfma_f32_16x16x32_bf16(                             \
        __builtin_bit_cast(bf16x8, sfrag[(c)]),                               \
        __builtin_bit_cast(bf16x8, braw), a_, 0, 0, 0);                       \
  }
    {
      CHUNK(0) CHUNK(1) CHUNK(2) CHUNK(3)
      CHUNK(4) CHUNK(5) CHUNK(6) CHUNK(7)
    }
    if (b >= 17) {
      CHUNK(8) CHUNK(9) CHUNK(10) CHUNK(11)
      CHUNK(12) CHUNK(13) CHUNK(14) CHUNK(15)
    }
    if (b >= 33) {
      CHUNK(16) CHUNK(17) CHUNK(18) CHUNK(19)
      CHUNK(20) CHUNK(21) CHUNK(22) CHUNK(23)
    }
#undef CHUNK

    // ---- deferred solve of block pb (scr data ready since last iter) ----
    float acc_t[16];
    #pragma unroll
    for (int c = 0; c < 16; ++c)
      acc_t[c] = myscr[r16 * 20 + c];
    solve16(acc_t, wtriL[pb % 3]);

    // ---- pack block pb into its sfrag chunk ----
    const int cml = cstar & 7;
    const int vb  = 8 * (g & 1);
    uint4 packed;
    packed.x = f2bf(acc_t[vb + 0]) | (f2bf(acc_t[vb + 1]) << 16);
    packed.y = f2bf(acc_t[vb + 2]) | (f2bf(acc_t[vb + 3]) << 16);
    packed.z = f2bf(acc_t[vb + 4]) | (f2bf(acc_t[vb + 5]) << 16);
    packed.w = f2bf(acc_t[vb + 6]) | (f2bf(acc_t[vb + 7]) << 16);
    const bool part = ((g >> 1) == (pb & 1));
#define PACKW(base)                                                           \
  {                                                                           \
    _Pragma("unroll")                                                         \
    for (int c2 = 0; c2 < 8; ++c2)                                            \
      if (c2 == cml) {                                                        \
        if (part) sfrag[(base) + c2] = packed;                                \
      }                                                                       \
  }
    if (pb < 16) {
      PACKW(0)
    } else if (pb < 32) {
      PACKW(8)
    } else {
      PACKW(16)
    }
#undef PACKW

    // ---- correction MFMA: add block pb's contribution to block b ----
    {
      uint4 onlynew;
      onlynew.x = part ? packed.x : 0u;
      onlynew.y = part ? packed.y : 0u;
      onlynew.z = part ? packed.z : 0u;
      onlynew.w = part ? packed.w : 0u;
      const int slot = ((cml * 4 + g) ^ (r16 & 7)) * 8;
      uint4 braw;
      if (cstar < 8)
        braw = *(const uint4*)&Bs[cur][0][r16 >> 1][(r16 & 1) * 256 + slot];
      else if (cstar < 16)
        braw = *(const uint4*)&Bs[cur][1][r16 >> 1][(r16 & 1) * 256 + slot];
      else
        braw = *(const uint4*)&Bs[cur][2][r16 >> 1][(r16 & 1) * 256 + slot];
      ac0 = __builtin_amdgcn_mfma_f32_16x16x32_bf16(
          __builtin_bit_cast(bf16x8, onlynew), __builtin_bit_cast(bf16x8, braw),
          ac0, 0, 0, 0);
    }

    // ---- finalize block b's logits; stash for next iteration's solve ----
    f32x4 accsum = (ac0 + ac1) + (ac2 + ac3);
    accsum[0] += bflo(praw.x);
    accsum[1] += bfhi(praw.x);
    accsum[2] += bflo(praw.y);
    accsum[3] += bfhi(praw.y);
    #pragma unroll
    for (int i = 0; i < 4; ++i)
      myscr[(4 * g + i) * 20 + r16] = accsum[i];

    __syncthreads();   // publish staged B/wtri; prior LDS reads done
  }
#undef STAGE_W
#undef STAGE_B

  // ---- epilogue: solve block 48 and write output ----
  {
    float acc_t[16];
    #pragma unroll
    for (int c = 0; c < 16; ++c)
      acc_t[c] = myscr[r16 * 20 + c];
    solve16(acc_t, wtriL[(NBLK - 1) % 3]);
    const size_t orow = (size_t)(slab_off + rb + r16) * OUT_DIM;
    #pragma unroll
    for (int i = 0; i < 4; ++i) {
      int oc = 4 * g + i;
      int mi = NMID - OUT_DIM + oc;
      out[orow + oc] = (acc_t[oc] + bias[mi]) * (float)ex[mi];
    }
  }
}

// ---------------------------------------------------------------------------
extern "C" void kernel_launch(void* const* d_in, const int* in_sizes, int n_in,
                              void* d_out, int out_size, void* d_ws, size_t ws_size,
                              hipStream_t stream) {
  const float* x      = (const float*)d_in[0];
  const float* weight = (const float*)d_in[1];
  const float* bias   = (const float*)d_in[2];
  const int*   conn   = (const int*)d_in[3];
  const int*   ex     = (const int*)d_in[4];

  char* ws = (char*)d_ws;
  size_t off = 0;
  unsigned short* effX = (unsigned short*)(ws + off); off += (size_t)NMID * INPUT_DIM * 2;
  unsigned short* effM = (unsigned short*)(ws + off); off += (size_t)NMID * MROW * 2;
  float*          cvec = (float*)(ws + off);          off += (size_t)NMID * 4;
  unsigned short* wpk  = (unsigned short*)(ws + off); off += (size_t)NBLK * 256 * 2;
  off = (off + 255) & ~(size_t)255;
  const size_t fixed = off;

  // Pt slab sizing: smallest power-of-two slab count that fits ws.
  int nslabs = 1;
  while (nslabs < 16 &&
         fixed + (size_t)NMID * (BATCH / nslabs) * 2 > ws_size)
    nslabs <<= 1;
  const int slabsz = BATCH / nslabs;
  unsigned short* Pt = (unsigned short*)(ws + fixed);

  prep_efft<<<dim3(16, 13), 256, 0, stream>>>(weight, conn, ex, effX, effM);
  prep_cvec<<<dim3(NMID), 64, 0, stream>>>(effM, weight, conn, ex, bias, cvec);
  prep_wpack<<<dim3(NBLK), 256, 0, stream>>>(weight, conn, ex, cvec, wpk);

  for (int s = 0; s < nslabs; ++s) {
    pgemm<<<dim3(slabsz / 64), 256, 0, stream>>>(
        x, effX, Pt, s * slabsz, slabsz);
    net_main<<<dim3(slabsz / 64), 256, 0, stream>>>(
        Pt, effM, wpk, bias, ex, (float*)d_out, s * slabsz, slabsz);
  }
}